// Round 3
// baseline (186.073 us; speedup 1.0000x reference)
//
#include <hip/hip_runtime.h>

#define DEVI __device__ __forceinline__

constexpr int N_ = 2, C_ = 80, H_ = 32, W_ = 40, HW_ = H_ * W_, HWC_ = HW_ * C_;
constexpr int KTOP = 1000, M2_ = 196;
constexpr int IMH = 256, IMW = 320;
constexpr int BUFCAP = 4096;
constexpr int NB = 2048;      // float-derived bins
constexpr int KB = 16;        // hist slices per image
constexpr int SLICE = HWC_ / KB; // 6400

// output layout (floats): bx[2][100][4] | sc[2][100] | lb[2][100] | prob[2][100][196] | vf[2][100]
constexpr int O_SC = 800, O_LB = 1000, O_PB = 1200, O_VF = 40400;

DEVI unsigned long long mapd(double v) {
  unsigned long long u = (unsigned long long)__double_as_longlong(v);
  return (u & 0x8000000000000000ull) ? ~u : (u | 0x8000000000000000ull);
}
DEVI double unmapd(unsigned long long k) {
  unsigned long long u = (k & 0x8000000000000000ull) ? (k ^ 0x8000000000000000ull) : ~k;
  return __longlong_as_double((long long)u);
}
DEVI int binof(unsigned long long k) {
  double v = unmapd(k);
  unsigned b = __float_as_uint((float)v);
  int bin = (int)(b >> 16) - 0x3800;
  return bin < 0 ? 0 : (bin > NB - 1 ? NB - 1 : bin);
}

// ---- K1: keys + per-slice LDS hist + mask transpose/sigmoid + weight tables ----
__global__ __launch_bounds__(1024) void k_pre(const float* cls, const float* cent, const float* bm,
                                              unsigned long long* keys, unsigned* ghist,
                                              float* msig, float* wr, float* wc) {
  int b = blockIdx.x, tid = threadIdx.x;
  if (b < N_ * KB) {
    __shared__ unsigned hist[NB];
    __shared__ double ce[HW_];
    int n = b / KB, sb = b % KB;
    size_t base = (size_t)n * HWC_ + (size_t)sb * SLICE;
    for (int j = tid; j < NB; j += 1024) hist[j] = 0;
    for (int j = tid; j < HW_; j += 1024) ce[j] = 1.0 / (1.0 + exp(-(double)cent[n * HW_ + j]));
    __syncthreads();
    #pragma unroll
    for (int it = 0; it < 7; ++it) {
      int j = it * 1024 + tid;
      if (j < SLICE) {
        size_t t = base + j;
        int hw = j % HW_;                       // base is a multiple of HW_
        double a = (double)cls[t];
        double s = 1.0 / (1.0 + exp(-a));
        double v = (s > 0.05) ? s * ce[hw] : -1e9;
        unsigned long long k = mapd(v);
        keys[t] = k;
        if (k >> 63) atomicAdd(&hist[binof(k)], 1u);
      }
    }
    __syncthreads();
    unsigned* gh = ghist + ((size_t)n * KB + sb) * NB;
    for (int j = tid; j < NB; j += 1024) gh[j] = hist[j];
  } else if (b < N_ * KB + 140) {
    __shared__ float tile[4][32][33];
    int g = tid >> 8, sub = tid & 255;
    int tt = (b - N_ * KB) * 4 + g;             // 0..559
    int n = tt / 280, r = tt % 280, rqt = r / 7, ct = r % 7;
    int tx = sub & 31, ty = sub >> 5;           // 32x8
    int rq0 = rqt * 32, c0 = ct * 32;
    for (int i = 0; i < 4; ++i) {
      int cc = c0 + ty + i * 8, rq = rq0 + tx;
      if (cc < M2_) {
        float v = bm[((size_t)n * M2_ + cc) * HW_ + rq];
        tile[g][ty + i * 8][tx] = 1.f / (1.f + expf(-v));
      }
    }
    __syncthreads();
    for (int i = 0; i < 4; ++i) {
      int rq = rq0 + ty + i * 8, cc = c0 + tx;
      if (cc < M2_) msig[((size_t)n * HW_ + rq) * M2_ + cc] = tile[g][tx][ty + i * 8];
    }
  } else {
    int t = tid;
    if (t < H_) {
      int r = t; float acc = 0.f; wr[0 * H_ + r] = 0.f;
      for (int x = 0; x < IMH; ++x) {
        float src = ((float)x + 0.5f) * ((float)H_ / (float)IMH) - 0.5f;
        src = fminf(fmaxf(src, 0.f), (float)(H_ - 1));
        int i0 = (int)floorf(src); int i1 = min(i0 + 1, H_ - 1);
        float lam = src - (float)i0;
        float w = ((r == i0) ? (1.f - lam) : 0.f) + ((r == i1) ? lam : 0.f);
        acc += w; wr[(x + 1) * H_ + r] = acc;
      }
    } else if (t < H_ + W_) {
      int q = t - H_; float acc = 0.f; wc[0 * W_ + q] = 0.f;
      for (int y = 0; y < IMW; ++y) {
        float src = ((float)y + 0.5f) * ((float)W_ / (float)IMW) - 0.5f;
        src = fminf(fmaxf(src, 0.f), (float)(W_ - 1));
        int i0 = (int)floorf(src); int i1 = min(i0 + 1, W_ - 1);
        float lam = src - (float)i0;
        float w = ((q == i0) ? (1.f - lam) : 0.f) + ((q == i1) ? lam : 0.f);
        acc += w; wc[(y + 1) * W_ + q] = acc;
      }
    }
  }
}

// ---- K2: per-image scan->compact->sort->decode->NMS->partition->outputs ----
struct PhA { unsigned long long K[BUFCAP]; unsigned I[BUFCAP]; };
struct PhB {
  double b0[1024], b1[1024], b2[1024], b3[1024];
  float scf[1024];
  unsigned short ml[16][128];
  unsigned char labT[1024], vld8[1024], kept[1024];
};
union SelU { PhA a; PhB b; };

__global__ __launch_bounds__(1024) void k_select(const unsigned long long* keys, const unsigned* ghist,
                                                 const float* loc, const float* breg,
                                                 int* rg, int* selA, int* vfA, float* out) {
  __shared__ SelU sh;
  __shared__ unsigned wtot[16], wabove[16];
  __shared__ unsigned sD, sCnt;
  __shared__ unsigned wcnt[16], woff[16], Stot;
  __shared__ int lsel[100], lvf[100];
  int n = blockIdx.x, tid = threadIdx.x, lane = tid & 63, wid = tid >> 6;

  // -- reduce 16 part-hists; thread owns bins 2tid, 2tid+1 --
  unsigned a = 0, bv = 0;
  {
    const unsigned* gh = ghist + (size_t)n * KB * NB;
    #pragma unroll
    for (int q = 0; q < KB; ++q) { a += gh[q * NB + 2 * tid]; bv += gh[q * NB + 2 * tid + 1]; }
  }
  if (tid == 0) { sD = 0; sCnt = 0; }
  // -- suffix scan (higher tid = higher bin) --
  unsigned s = a + bv, suf = s;
  for (int off = 1; off < 64; off <<= 1) {
    unsigned v = __shfl_down(suf, off);
    if (lane + off < 64) suf += v;
  }
  if (lane == 0) wtot[wid] = suf;
  __syncthreads();
  if (tid == 0) { unsigned acc = 0; for (int w = 15; w >= 0; --w) { wabove[w] = acc; acc += wtot[w]; } }
  __syncthreads();
  unsigned above = (suf - s) + wabove[wid];
  if (above < 1000u && above + bv >= 1000u) sD = (unsigned)(2 * tid + 1);
  if (above + bv < 1000u && above + bv + a >= 1000u) sD = (unsigned)(2 * tid);
  __syncthreads();
  unsigned D = sD;

  // -- compact bin>=D with unroll-8 MLP + wave-aggregated LDS counter --
  const unsigned long long* kb = keys + (size_t)n * HWC_;
  for (int base2 = 0; base2 < 100; base2 += 8) {
    int nu = min(8, 100 - base2);
    unsigned long long kk[8];
    for (int u = 0; u < nu; ++u) kk[u] = kb[(base2 + u) * 1024 + tid];
    for (int u = 0; u < nu; ++u) {
      unsigned long long k = kk[u];
      bool win = (k >> 63) && (unsigned)binof(k) >= D;
      unsigned long long mb = __ballot(win);
      if (mb) {
        int lead = __builtin_ctzll(mb);
        unsigned offw = 0;
        if (lane == lead) offw = atomicAdd(&sCnt, (unsigned)__popcll(mb));
        offw = (unsigned)__shfl((int)offw, lead);
        if (win) {
          unsigned pos = offw + (unsigned)__popcll(mb & ((1ull << lane) - 1ull));
          if (pos < BUFCAP) {
            int tl = (base2 + u) * 1024 + tid;
            sh.a.K[pos] = k;
            sh.a.I[pos] = (unsigned)((tl % HW_) * C_ + tl / HW_);  // logical [HW,C] index
          }
        }
      }
    }
  }
  __syncthreads();
  int cnt = (int)sCnt; if (cnt > BUFCAP) cnt = BUFCAP;
  int P = 1024; while (P < cnt) P <<= 1;
  for (int j = cnt + tid; j < P; j += 1024) { sh.a.K[j] = 0ull; sh.a.I[j] = 0xFFFFFFFFu; }

  // -- bitonic sort by (key desc, idx asc): one compare-exchange per thread per round --
  for (int sz = 2; sz <= P; sz <<= 1) {
    for (int st = sz >> 1; st > 0; st >>= 1) {
      __syncthreads();
      for (int p = tid; p < (P >> 1); p += 1024) {
        int i = ((p & ~(st - 1)) << 1) | (p & (st - 1));
        int j = i | st;
        bool up = ((i & sz) == 0);
        unsigned long long k1 = sh.a.K[i], k2 = sh.a.K[j];
        unsigned i1 = sh.a.I[i], i2 = sh.a.I[j];
        bool bef = (k1 > k2) || (k1 == k2 && i1 < i2);
        if (bef != up) { sh.a.K[i] = k2; sh.a.K[j] = k1; sh.a.I[i] = i2; sh.a.I[j] = i1; }
      }
    }
  }
  __syncthreads();

  // -- decode top-1000 (f64, exact vs np ref) into registers --
  unsigned long long key = (tid < KTOP) ? sh.a.K[tid] : 0ull;
  unsigned idx = (tid < KTOP) ? sh.a.I[tid] : 0xFFFFFFFFu;
  __syncthreads();  // union switch: PhA dead after this point

  double c0d = 0, c1d = 0, c2d = 0, c3d = 0, sc = 0;
  int lb = 1, valid = 0;
  if (tid < KTOP) {
    double v = unmapd(key);
    valid = (v > -5e8) && (idx < (unsigned)HWC_);
    if (idx >= (unsigned)HWC_) idx = 0;
    int hw = (int)(idx / C_), c = (int)(idx % C_);
    double lx = (double)loc[hw * 2 + 0], ly = (double)loc[hw * 2 + 1];
    const float* rg4 = breg + (size_t)n * 4 * HW_;
    double r0 = (double)rg4[0 * HW_ + hw], r1 = (double)rg4[1 * HW_ + hw];
    double r2 = (double)rg4[2 * HW_ + hw], r3 = (double)rg4[3 * HW_ + hw];
    double b0 = lx - r0, b1 = ly - r1, b2 = lx + r2, b3 = ly + r3;
    sc = valid ? sqrt(v) : 0.0;
    int bi0 = (int)b0, bi1 = (int)b1, bi2 = (int)b2, bi3 = (int)b3;
    int x1 = max(bi0, 0), x2 = min(bi2, IMH - 1), y1 = max(bi1, 0), y2 = min(bi3, IMW - 1);
    int rok = (x1 < x2) && (y1 < x2) && (y1 < y2);   // ref bug replicated
    int x1c = min(max(x1, 0), IMH), x2c = min(max(x2, 0), IMH);
    int y1c = min(max(y1, 0), IMW), y2c = min(max(y2, 0), IMW);
    int area = max((x2c - x1c) * (y2c - y1c), 1);
    c0d = fmin(fmax(b0, 0.0), (double)(IMW - 1));
    c1d = fmin(fmax(b1, 0.0), (double)(IMH - 1));
    c2d = fmin(fmax(b2, 0.0), (double)(IMH - 1) + 0.0);  // note: x2 clipped to w-1? see below
    // reference: x in [0, w-1], y in [0, h-1]; boxes (x1,y1,x2,y2) with x∈width(=IMW), y∈height(=IMH)
    c2d = fmin(fmax(b2, 0.0), (double)(IMW - 1));
    c3d = fmin(fmax(b3, 0.0), (double)(IMH - 1));
    lb = c + 1;
    int* r8 = rg + ((size_t)n * 1024 + tid) * 8;
    r8[0] = x1c; r8[1] = x2c; r8[2] = y1c; r8[3] = y2c; r8[4] = area; r8[5] = rok;
  }
  // -- stash into PhB LDS --
  sh.b.b0[tid] = c0d; sh.b.b1[tid] = c1d; sh.b.b2[tid] = c2d; sh.b.b3[tid] = c3d;
  sh.b.scf[tid] = (float)sc;
  sh.b.labT[tid] = (unsigned char)lb;
  sh.b.vld8[tid] = (unsigned char)valid;
  sh.b.kept[tid] = 0;
  __syncthreads();

  // -- NMS: wave w handles classes w+1, w+17, ... (5 each); register kept-bitmasks --
  for (int q = 0; q < 5; ++q) {
    int cls = 1 + wid + q * 16;
    if (cls > C_) break;
    unsigned short* ml = sh.b.ml[wid];
    int m = 0;
    for (int base = 0; base < 1024; base += 64) {
      int e = base + lane;
      bool pred = (e < KTOP) && sh.b.vld8[e] && ((int)sh.b.labT[e] == cls);
      unsigned long long bb = __ballot(pred);
      if (pred) {
        int pos = m + (int)__popcll(bb & ((1ull << lane) - 1ull));
        if (pos < 128) ml[pos] = (unsigned short)e;
      }
      m += (int)__popcll(bb);
    }
    if (m > 128) m = 128;
    if (m > 0) {
      unsigned long long k0 = (m >= 64) ? ~0ull : ((1ull << m) - 1ull);
      unsigned long long k1m = (m > 64) ? ((m >= 128) ? ~0ull : ((1ull << (m - 64)) - 1ull)) : 0ull;
      for (int i = 0; i < m; ++i) {
        bool alive = (i < 64) ? ((k0 >> i) & 1ull) : ((k1m >> (i - 64)) & 1ull);
        if (!alive) continue;
        int ei = ml[i];
        double x1 = sh.b.b0[ei], y1 = sh.b.b1[ei], x2 = sh.b.b2[ei], y2 = sh.b.b3[ei];
        double ai = (x2 - x1 + 1.0) * (y2 - y1 + 1.0);
        {
          int j = lane;
          bool ok = (j < m) && (j > i);
          int ej = ok ? ml[j] : ml[0];
          double u1 = sh.b.b0[ej], v1 = sh.b.b1[ej], u2 = sh.b.b2[ej], v2 = sh.b.b3[ej];
          double aj = (u2 - u1 + 1.0) * (v2 - v1 + 1.0);
          double ltx = fmax(x1, u1), lty = fmax(y1, v1), rbx = fmin(x2, u2), rby = fmin(y2, v2);
          double iw = fmax(rbx - ltx + 1.0, 0.0), ih = fmax(rby - lty + 1.0, 0.0);
          double inter = iw * ih, uni = ai + aj - inter;
          bool sup = ok && (inter / fmax(uni, 1e-6) > 0.6);
          k0 &= ~__ballot(sup);
        }
        if (m > 64) {
          int j = 64 + lane;
          bool ok = (j < m) && (j > i);
          int ej = ok ? ml[j] : ml[0];
          double u1 = sh.b.b0[ej], v1 = sh.b.b1[ej], u2 = sh.b.b2[ej], v2 = sh.b.b3[ej];
          double aj = (u2 - u1 + 1.0) * (v2 - v1 + 1.0);
          double ltx = fmax(x1, u1), lty = fmax(y1, v1), rbx = fmin(x2, u2), rby = fmin(y2, v2);
          double iw = fmax(rbx - ltx + 1.0, 0.0), ih = fmax(rby - lty + 1.0, 0.0);
          double inter = iw * ih, uni = ai + aj - inter;
          bool sup = ok && (inter / fmax(uni, 1e-6) > 0.6);
          k1m &= ~__ballot(sup);
        }
      }
      for (int j = lane; j < m; j += 64) {
        bool kb2 = (j < 64) ? ((k0 >> j) & 1ull) : ((k1m >> (j - 64)) & 1ull);
        if (kb2) sh.b.kept[ml[j]] = 1;
      }
    }
  }
  __syncthreads();

  // -- stable partition by kept flag -> 100 slots; write outputs --
  int kp = (tid < KTOP) ? (int)sh.b.kept[tid] : 0;
  unsigned long long bal = __ballot(kp != 0);
  int posw = (int)__popcll(bal & ((1ull << lane) - 1ull));
  if (lane == 0) wcnt[wid] = (unsigned)__popcll(bal);
  __syncthreads();
  if (tid == 0) { unsigned acc = 0; for (int i = 0; i < 16; ++i) { woff[i] = acc; acc += wcnt[i]; } Stot = acc; }
  __syncthreads();
  int posK = (int)woff[wid] + posw;
  int S = (int)Stot;
  if (tid < KTOP) {
    if (kp) { if (posK < 100) { lsel[posK] = tid; lvf[posK] = 1; } }
    else { int slot = S + (tid - posK); if (slot < 100) { lsel[slot] = tid; lvf[slot] = 0; } }
  }
  __syncthreads();
  if (tid < 100) {
    int k = lsel[tid], vf = lvf[tid];
    selA[n * 128 + tid] = k; vfA[n * 128 + tid] = vf;
    out[(n * 100 + tid) * 4 + 0] = (float)sh.b.b0[k];
    out[(n * 100 + tid) * 4 + 1] = (float)sh.b.b1[k];
    out[(n * 100 + tid) * 4 + 2] = (float)sh.b.b2[k];
    out[(n * 100 + tid) * 4 + 3] = (float)sh.b.b3[k];
    out[O_SC + n * 100 + tid] = vf ? sh.b.scf[k] : 0.f;
    out[O_LB + n * 100 + tid] = (float)sh.b.labT[k];
    out[O_VF + n * 100 + tid] = (float)vf;
  }
}

// ---- K3: mask prob for the 200 selected slots (separable region sum) ----
__global__ __launch_bounds__(256) void k_prob(const int* selA, const int* vfA, const int* rg,
                                              const float* msig, const float* wr, const float* wc,
                                              float* out) {
  int t = blockIdx.x, n = blockIdx.y, tid = threadIdx.x;
  int k = selA[n * 128 + t], vf = vfA[n * 128 + t];
  const int* r8 = rg + ((size_t)n * 1024 + k) * 8;
  int x1c = r8[0], x2c = r8[1], y1c = r8[2], y2c = r8[3], area = r8[4], rok = r8[5];
  __shared__ float A[H_], B[W_];
  if (tid < H_) A[tid] = wr[x2c * H_ + tid] - wr[x1c * H_ + tid];
  else if (tid < H_ + W_) { int q = tid - H_; B[q] = wc[y2c * W_ + q] - wc[y1c * W_ + q]; }
  __syncthreads();
  if (tid < M2_) {
    float acc = 0.f;
    if (rok && vf) {
      for (int r = 0; r < H_; ++r) {
        float ar = A[r];
        if (ar == 0.f) continue;
        const float* mrow = msig + ((size_t)(n * H_ + r) * W_) * M2_ + tid;
        float rs = 0.f;
        for (int q = 0; q < W_; ++q) {
          float bq = B[q];
          if (bq != 0.f) rs += bq * mrow[q * M2_];
        }
        acc += ar * rs;
      }
      acc /= (float)area;
    }
    out[O_PB + (size_t)(n * 100 + t) * M2_ + tid] = acc;
  }
}

extern "C" void kernel_launch(void* const* d_in, const int* in_sizes, int n_in,
                              void* d_out, int out_size, void* d_ws, size_t ws_size,
                              hipStream_t stream) {
  (void)in_sizes; (void)n_in; (void)out_size; (void)ws_size;
  const float* locations = (const float*)d_in[0];
  const float* box_cls   = (const float*)d_in[1];
  const float* box_reg   = (const float*)d_in[2];
  const float* cent      = (const float*)d_in[3];
  const float* box_mask  = (const float*)d_in[4];
  float* out = (float*)d_out;

  char* ws = (char*)d_ws;
  size_t off = 0;
  auto alloc = [&](size_t bytes) -> void* {
    void* p = ws + off;
    off = (off + bytes + 255) & ~(size_t)255;
    return p;
  };
  unsigned long long* keys = (unsigned long long*)alloc((size_t)N_ * HWC_ * 8);
  unsigned* ghist          = (unsigned*)alloc((size_t)N_ * KB * NB * 4);
  int* rg                  = (int*)alloc((size_t)N_ * 1024 * 8 * 4);
  int* selA                = (int*)alloc((size_t)N_ * 128 * 4);
  int* vfA                 = (int*)alloc((size_t)N_ * 128 * 4);
  float* msig              = (float*)alloc((size_t)N_ * HW_ * M2_ * 4);
  float* wr                = (float*)alloc((size_t)(IMH + 1) * H_ * 4);
  float* wc                = (float*)alloc((size_t)(IMW + 1) * W_ * 4);

  k_pre<<<N_ * KB + 140 + 1, 1024, 0, stream>>>(box_cls, cent, box_mask, keys, ghist, msig, wr, wc);
  k_select<<<N_, 1024, 0, stream>>>(keys, ghist, locations, box_reg, rg, selA, vfA, out);
  k_prob<<<dim3(100, N_), 256, 0, stream>>>(selA, vfA, rg, msig, wr, wc, out);
}

// Round 4
// 113.467 us; speedup vs baseline: 1.6399x; 1.6399x over previous
//
#include <hip/hip_runtime.h>

#define DEVI __device__ __forceinline__

constexpr int N_ = 2, C_ = 80, H_ = 32, W_ = 40, HW_ = H_ * W_, HWC_ = HW_ * C_;
constexpr int KTOP = 1000, M2_ = 196;
constexpr int IMH = 256, IMW = 320;
constexpr int BUFCAP = 4096;
constexpr int NB = 2048;      // float-derived bins
constexpr int KB = 16;        // hist slices per image
constexpr int SLICE = HWC_ / KB; // 6400 = 5*HW_

// output layout (floats): bx[2][100][4] | sc[2][100] | lb[2][100] | prob[2][100][196] | vf[2][100]
constexpr int O_SC = 800, O_LB = 1000, O_PB = 1200, O_VF = 40400;

DEVI unsigned long long mapd(double v) {
  unsigned long long u = (unsigned long long)__double_as_longlong(v);
  return (u & 0x8000000000000000ull) ? ~u : (u | 0x8000000000000000ull);
}
DEVI double unmapd(unsigned long long k) {
  unsigned long long u = (k & 0x8000000000000000ull) ? (k ^ 0x8000000000000000ull) : ~k;
  return __longlong_as_double((long long)u);
}
DEVI int binof(unsigned long long k) {
  double v = unmapd(k);
  unsigned b = __float_as_uint((float)v);
  int bin = (int)(b >> 16) - 0x3800;
  return bin < 0 ? 0 : (bin > NB - 1 ? NB - 1 : bin);
}

// ---- K1: keys + per-slice LDS hist + mask transpose/sigmoid + weight tables (proven r3) ----
__global__ __launch_bounds__(1024) void k_pre(const float* cls, const float* cent, const float* bm,
                                              unsigned long long* keys, unsigned* ghist,
                                              float* msig, float* wr, float* wc) {
  int b = blockIdx.x, tid = threadIdx.x;
  if (b < N_ * KB) {
    __shared__ unsigned hist[NB];
    __shared__ double ce[HW_];
    int n = b / KB, sb = b % KB;
    size_t base = (size_t)n * HWC_ + (size_t)sb * SLICE;
    for (int j = tid; j < NB; j += 1024) hist[j] = 0;
    for (int j = tid; j < HW_; j += 1024) ce[j] = 1.0 / (1.0 + exp(-(double)cent[n * HW_ + j]));
    __syncthreads();
    #pragma unroll
    for (int it = 0; it < 7; ++it) {
      int j = it * 1024 + tid;
      if (j < SLICE) {
        size_t t = base + j;
        int hw = j % HW_;                       // base is a multiple of HW_
        double a = (double)cls[t];
        double s = 1.0 / (1.0 + exp(-a));
        double v = (s > 0.05) ? s * ce[hw] : -1e9;
        unsigned long long k = mapd(v);
        keys[t] = k;
        if (k >> 63) atomicAdd(&hist[binof(k)], 1u);
      }
    }
    __syncthreads();
    unsigned* gh = ghist + ((size_t)n * KB + sb) * NB;
    for (int j = tid; j < NB; j += 1024) gh[j] = hist[j];
  } else if (b < N_ * KB + 140) {
    __shared__ float tile[4][32][33];
    int g = tid >> 8, sub = tid & 255;
    int tt = (b - N_ * KB) * 4 + g;             // 0..559
    int n = tt / 280, r = tt % 280, rqt = r / 7, ct = r % 7;
    int tx = sub & 31, ty = sub >> 5;           // 32x8
    int rq0 = rqt * 32, c0 = ct * 32;
    for (int i = 0; i < 4; ++i) {
      int cc = c0 + ty + i * 8, rq = rq0 + tx;
      if (cc < M2_) {
        float v = bm[((size_t)n * M2_ + cc) * HW_ + rq];
        tile[g][ty + i * 8][tx] = 1.f / (1.f + expf(-v));
      }
    }
    __syncthreads();
    for (int i = 0; i < 4; ++i) {
      int rq = rq0 + ty + i * 8, cc = c0 + tx;
      if (cc < M2_) msig[((size_t)n * HW_ + rq) * M2_ + cc] = tile[g][tx][ty + i * 8];
    }
  } else {
    int t = tid;
    if (t < H_) {
      int r = t; float acc = 0.f; wr[0 * H_ + r] = 0.f;
      for (int x = 0; x < IMH; ++x) {
        float src = ((float)x + 0.5f) * ((float)H_ / (float)IMH) - 0.5f;
        src = fminf(fmaxf(src, 0.f), (float)(H_ - 1));
        int i0 = (int)floorf(src); int i1 = min(i0 + 1, H_ - 1);
        float lam = src - (float)i0;
        float w = ((r == i0) ? (1.f - lam) : 0.f) + ((r == i1) ? lam : 0.f);
        acc += w; wr[(x + 1) * H_ + r] = acc;
      }
    } else if (t < H_ + W_) {
      int q = t - H_; float acc = 0.f; wc[0 * W_ + q] = 0.f;
      for (int y = 0; y < IMW; ++y) {
        float src = ((float)y + 0.5f) * ((float)W_ / (float)IMW) - 0.5f;
        src = fminf(fmaxf(src, 0.f), (float)(W_ - 1));
        int i0 = (int)floorf(src); int i1 = min(i0 + 1, W_ - 1);
        float lam = src - (float)i0;
        float w = ((q == i0) ? (1.f - lam) : 0.f) + ((q == i1) ? lam : 0.f);
        acc += w; wc[(y + 1) * W_ + q] = acc;
      }
    }
  }
}

// ---- K2: parallel compact — 32 blocks; each computes D redundantly, owns one slice ----
__global__ __launch_bounds__(1024) void k_compact(const unsigned long long* keys, const unsigned* ghist,
                                                  unsigned long long* bufK, unsigned* bufI, unsigned* cntG) {
  __shared__ unsigned wtot[16], wabove[16], sliceCnt[16], sliceOff[17];
  __shared__ unsigned sD, lcnt;
  int b = blockIdx.x, n = b >> 4, sb = b & 15;
  int tid = threadIdx.x, lane = tid & 63, wid = tid >> 6;
  const unsigned* gh = ghist + (size_t)n * KB * NB;
  unsigned a = 0, bv = 0;
  #pragma unroll
  for (int q = 0; q < KB; ++q) { a += gh[q * NB + 2 * tid]; bv += gh[q * NB + 2 * tid + 1]; }
  if (tid == 0) { sD = 0; lcnt = 0; }
  unsigned s = a + bv, suf = s;
  for (int off = 1; off < 64; off <<= 1) {
    unsigned v = __shfl_down(suf, off);
    if (lane + off < 64) suf += v;
  }
  if (lane == 0) wtot[wid] = suf;
  __syncthreads();
  if (tid == 0) { unsigned acc = 0; for (int w = 15; w >= 0; --w) { wabove[w] = acc; acc += wtot[w]; } }
  __syncthreads();
  unsigned above = (suf - s) + wabove[wid];
  if (above < 1000u && above + bv >= 1000u) sD = (unsigned)(2 * tid + 1);
  if (above + bv < 1000u && above + bv + a >= 1000u) sD = (unsigned)(2 * tid);
  __syncthreads();
  unsigned D = sD;

  // per-slice counts of bin >= D: wave w handles slice w
  {
    unsigned acc = 0;
    for (int bin = (int)D + lane; bin < NB; bin += 64) acc += gh[wid * NB + bin];
    for (int off = 32; off; off >>= 1) acc += __shfl_down(acc, off);
    if (lane == 0) sliceCnt[wid] = acc;
  }
  __syncthreads();
  if (tid == 0) {
    unsigned acc = 0;
    for (int q = 0; q < KB; ++q) { sliceOff[q] = acc; acc += sliceCnt[q]; }
    sliceOff[KB] = acc;
    if (sb == 0) cntG[n] = acc;
  }
  __syncthreads();
  unsigned myStart = sliceOff[sb];

  const unsigned long long* kb = keys + (size_t)n * HWC_ + (size_t)sb * SLICE;
  for (int it = 0; it < 7; ++it) {
    int j = it * 1024 + tid;
    bool win = false; unsigned long long k = 0;
    if (j < SLICE) { k = kb[j]; win = (k >> 63) && (unsigned)binof(k) >= D; }
    unsigned long long mb = __ballot(win);
    if (mb) {
      int lead = __builtin_ctzll(mb);
      unsigned offw = 0;
      if (lane == lead) offw = atomicAdd(&lcnt, (unsigned)__popcll(mb));
      offw = (unsigned)__shfl((int)offw, lead);
      if (win) {
        unsigned pos = myStart + offw + (unsigned)__popcll(mb & ((1ull << lane) - 1ull));
        if (pos < BUFCAP) {
          int hw = j % HW_, c = sb * 5 + j / HW_;        // SLICE = 5*HW_
          bufK[(size_t)n * BUFCAP + pos] = k;
          bufI[(size_t)n * BUFCAP + pos] = (unsigned)(hw * C_ + c); // logical [HW,C] index
        }
      }
    }
  }
}

// ---- K3: serial core — sort (shfl-accelerated bitonic) + f64 decode ----
struct SortSh { unsigned long long K[BUFCAP]; unsigned I[BUFCAP]; };

__global__ __launch_bounds__(1024) void k_sortdec(const unsigned long long* bufK, const unsigned* bufI,
                                                  const unsigned* cntG, const float* loc, const float* breg,
                                                  double* bxd, double* scd, int* lab, int* vld, int* rg,
                                                  unsigned* keepg) {
  __shared__ SortSh sh;
  int n = blockIdx.x, tid = threadIdx.x;
  keepg[n * 1024 + tid] = 0;
  unsigned cnt = cntG[n]; if (cnt > BUFCAP) cnt = BUFCAP;
  int P = 1024; while (P < (int)cnt) P <<= 1;
  for (int j = tid; j < P; j += 1024) {
    if (j < (int)cnt) { sh.K[j] = bufK[(size_t)n * BUFCAP + j]; sh.I[j] = bufI[(size_t)n * BUFCAP + j]; }
    else { sh.K[j] = 0ull; sh.I[j] = 0xFFFFFFFFu; }
  }
  __syncthreads();
  int E = P >> 10; // elements per thread: 1,2,4
  for (int sz = 2; sz <= P; sz <<= 1) {
    // LDS rounds for strides >= 64
    for (int st = sz >> 1; st >= 64; st >>= 1) {
      for (int p = tid; p < (P >> 1); p += 1024) {
        int i = ((p & ~(st - 1)) << 1) | (p & (st - 1));
        int j = i | st;
        bool up = ((i & sz) == 0);
        unsigned long long k1 = sh.K[i], k2 = sh.K[j];
        unsigned i1 = sh.I[i], i2 = sh.I[j];
        bool bef = (k1 > k2) || (k1 == k2 && i1 < i2);
        if (bef != up) { sh.K[i] = k2; sh.K[j] = k1; sh.I[i] = i2; sh.I[j] = i1; }
      }
      __syncthreads();
    }
    // in-wave shfl rounds for strides <= 32 (partner lane = lane^st, same wave)
    {
      int st0 = ((sz >> 1) < 32) ? (sz >> 1) : 32;
      for (int e = 0; e < E; ++e) {
        int elem = tid + (e << 10);
        unsigned long long k = sh.K[elem];
        unsigned ii = sh.I[elem];
        bool dir = ((elem & sz) == 0);
        for (int st = st0; st >= 1; st >>= 1) {
          unsigned long long ko = __shfl_xor(k, st);
          unsigned io = __shfl_xor(ii, st);
          bool low = ((elem & st) == 0);
          bool first = (k > ko) || (k == ko && ii < io);
          bool take_mine = first ^ (!low) ^ (!dir);
          if (!take_mine) { k = ko; ii = io; }
        }
        sh.K[elem] = k; sh.I[elem] = ii;
      }
      __syncthreads();
    }
  }

  // decode top-1000 (f64, exact vs np ref) -> per-candidate globals
  if (tid < KTOP) {
    unsigned long long key = sh.K[tid];
    unsigned idx = sh.I[tid];
    double v = unmapd(key);
    int valid = (v > -5e8) && (idx < (unsigned)HWC_);
    if (idx >= (unsigned)HWC_) idx = 0;
    int hw = (int)(idx / C_), c = (int)(idx % C_);
    double lx = (double)loc[hw * 2 + 0], ly = (double)loc[hw * 2 + 1];
    const float* rg4 = breg + (size_t)n * 4 * HW_;
    double r0 = (double)rg4[0 * HW_ + hw], r1 = (double)rg4[1 * HW_ + hw];
    double r2 = (double)rg4[2 * HW_ + hw], r3 = (double)rg4[3 * HW_ + hw];
    double b0 = lx - r0, b1 = ly - r1, b2 = lx + r2, b3 = ly + r3;
    double sc = valid ? sqrt(v) : 0.0;
    int bi0 = (int)b0, bi1 = (int)b1, bi2 = (int)b2, bi3 = (int)b3;
    int x1 = max(bi0, 0), x2 = min(bi2, IMH - 1), y1 = max(bi1, 0), y2 = min(bi3, IMW - 1);
    int rok = (x1 < x2) && (y1 < x2) && (y1 < y2);   // ref bug replicated
    int x1c = min(max(x1, 0), IMH), x2c = min(max(x2, 0), IMH);
    int y1c = min(max(y1, 0), IMW), y2c = min(max(y2, 0), IMW);
    int area = max((x2c - x1c) * (y2c - y1c), 1);
    double c0 = fmin(fmax(b0, 0.0), (double)(IMW - 1));
    double c1 = fmin(fmax(b1, 0.0), (double)(IMH - 1));
    double c2 = fmin(fmax(b2, 0.0), (double)(IMW - 1));
    double c3 = fmin(fmax(b3, 0.0), (double)(IMH - 1));
    size_t base = (size_t)n * 1024 + tid;
    bxd[base * 4 + 0] = c0; bxd[base * 4 + 1] = c1; bxd[base * 4 + 2] = c2; bxd[base * 4 + 3] = c3;
    scd[base] = sc; lab[base] = c + 1; vld[base] = valid;
    int* r8 = rg + base * 8;
    r8[0] = x1c; r8[1] = x2c; r8[2] = y1c; r8[3] = y2c; r8[4] = area; r8[5] = rok;
  }
}

// ---- K4: per-(image,class) greedy NMS (proven r2; 160 parallel blocks) ----
__global__ void k_nms(const double* bxd, const int* lab, const int* vld, unsigned* keepg) {
  int cls = blockIdx.x + 1, n = blockIdx.y, tid = threadIdx.x; // 64 threads = 1 wave
  __shared__ int mk[KTOP];
  __shared__ double mb0[KTOP], mb1[KTOP], mb2[KTOP], mb3[KTOP], ma[KTOP];
  __shared__ unsigned char kept[KTOP];
  int m = 0;
  for (int base = 0; base < KTOP; base += 64) {
    int t = base + tid;
    bool pred = (t < KTOP) && (lab[n * 1024 + t] == cls) && (vld[n * 1024 + t] != 0);
    unsigned long long bb = __ballot(pred);
    if (pred) {
      int pos = m + (int)__popcll(bb & ((1ull << tid) - 1ull));
      mk[pos] = t;
      const double* p = bxd + ((size_t)n * 1024 + t) * 4;
      double b0 = p[0], b1 = p[1], b2 = p[2], b3 = p[3];
      mb0[pos] = b0; mb1[pos] = b1; mb2[pos] = b2; mb3[pos] = b3;
      ma[pos] = (b2 - b0 + 1.0) * (b3 - b1 + 1.0);
      kept[pos] = 1;
    }
    m += (int)__popcll(bb);
  }
  __syncthreads();
  for (int i = 0; i < m; ++i) {
    if (kept[i]) {
      double x1 = mb0[i], y1 = mb1[i], x2 = mb2[i], y2 = mb3[i], ai = ma[i];
      for (int j = i + 1 + tid; j < m; j += 64) {
        double ltx = fmax(x1, mb0[j]), lty = fmax(y1, mb1[j]);
        double rbx = fmin(x2, mb2[j]), rby = fmin(y2, mb3[j]);
        double iw = fmax(rbx - ltx + 1.0, 0.0), ih = fmax(rby - lty + 1.0, 0.0);
        double inter = iw * ih;
        double uni = ai + ma[j] - inter;
        if (inter / fmax(uni, 1e-6) > 0.6) kept[j] = 0;
      }
    }
    __syncthreads();
  }
  for (int i = tid; i < m; i += 64) keepg[n * 1024 + mk[i]] = (unsigned)kept[i];
}

// ---- K5: fused stable partition (redundant per block) + outputs + mask prob (proven r2) ----
__global__ __launch_bounds__(256) void k_finish(const unsigned* keepg, const double* bxd,
                                                const double* scd, const int* lab, const int* rg,
                                                const float* msig, const float* wr, const float* wc,
                                                float* out) {
  int t = blockIdx.x, n = blockIdx.y, tid = threadIdx.x, lane = tid & 63, wid = tid >> 6;
  __shared__ int lsel[100], lvf[100];
  __shared__ unsigned woff[4]; __shared__ unsigned sS;
  __shared__ float A[H_], B[W_];

  int i0 = tid * 4;
  unsigned ff[4]; int lc = 0;
  for (int j = 0; j < 4; ++j) {
    int i = i0 + j;
    ff[j] = (i < KTOP) ? keepg[n * 1024 + i] : 0u;
    lc += (int)ff[j];
  }
  unsigned pre = (unsigned)lc;
  for (int off = 1; off < 64; off <<= 1) {
    unsigned v = __shfl_up(pre, off);
    if (lane >= off) pre += v;
  }
  if (lane == 63) woff[wid] = pre;
  __syncthreads();
  if (tid == 0) { unsigned acc = 0; for (int w = 0; w < 4; ++w) { unsigned tmp = woff[w]; woff[w] = acc; acc += tmp; } sS = acc; }
  __syncthreads();
  int kpre = (int)(woff[wid] + pre - (unsigned)lc);
  int S = (int)sS;
  for (int j = 0; j < 4; ++j) {
    int i = i0 + j;
    if (i < KTOP) {
      if (ff[j]) { if (kpre < 100) { lsel[kpre] = i; lvf[kpre] = 1; } kpre++; }
      else { int slot = S + (i - kpre); if (slot < 100) { lsel[slot] = i; lvf[slot] = 0; } }
    }
  }
  __syncthreads();

  int k = lsel[t], vf = lvf[t];
  if (tid == 0) {
    const double* bb = bxd + ((size_t)n * 1024 + k) * 4;
    out[(n * 100 + t) * 4 + 0] = (float)bb[0];
    out[(n * 100 + t) * 4 + 1] = (float)bb[1];
    out[(n * 100 + t) * 4 + 2] = (float)bb[2];
    out[(n * 100 + t) * 4 + 3] = (float)bb[3];
    out[O_SC + n * 100 + t] = vf ? (float)scd[n * 1024 + k] : 0.f;
    out[O_LB + n * 100 + t] = (float)lab[n * 1024 + k];
    out[O_VF + n * 100 + t] = (float)vf;
  }
  const int* r8 = rg + ((size_t)n * 1024 + k) * 8;
  int x1c = r8[0], x2c = r8[1], y1c = r8[2], y2c = r8[3], area = r8[4], rok = r8[5];
  if (tid < H_) A[tid] = wr[x2c * H_ + tid] - wr[x1c * H_ + tid];
  else if (tid < H_ + W_) { int q = tid - H_; B[q] = wc[y2c * W_ + q] - wc[y1c * W_ + q]; }
  __syncthreads();
  if (tid < M2_) {
    float acc = 0.f;
    if (rok && vf) {
      for (int r = 0; r < H_; ++r) {
        float ar = A[r];
        if (ar == 0.f) continue;
        const float* mrow = msig + ((size_t)(n * H_ + r) * W_) * M2_ + tid;
        float rs = 0.f;
        for (int q = 0; q < W_; ++q) {
          float bq = B[q];
          if (bq != 0.f) rs += bq * mrow[q * M2_];
        }
        acc += ar * rs;
      }
      acc /= (float)area;
    }
    out[O_PB + (size_t)(n * 100 + t) * M2_ + tid] = acc;
  }
}

extern "C" void kernel_launch(void* const* d_in, const int* in_sizes, int n_in,
                              void* d_out, int out_size, void* d_ws, size_t ws_size,
                              hipStream_t stream) {
  (void)in_sizes; (void)n_in; (void)out_size; (void)ws_size;
  const float* locations = (const float*)d_in[0];
  const float* box_cls   = (const float*)d_in[1];
  const float* box_reg   = (const float*)d_in[2];
  const float* cent      = (const float*)d_in[3];
  const float* box_mask  = (const float*)d_in[4];
  float* out = (float*)d_out;

  char* ws = (char*)d_ws;
  size_t off = 0;
  auto alloc = [&](size_t bytes) -> void* {
    void* p = ws + off;
    off = (off + bytes + 255) & ~(size_t)255;
    return p;
  };
  unsigned long long* keys = (unsigned long long*)alloc((size_t)N_ * HWC_ * 8);
  unsigned* ghist          = (unsigned*)alloc((size_t)N_ * KB * NB * 4);
  unsigned long long* bufK = (unsigned long long*)alloc((size_t)N_ * BUFCAP * 8);
  unsigned* bufI           = (unsigned*)alloc((size_t)N_ * BUFCAP * 4);
  unsigned* cntG           = (unsigned*)alloc(16 * 4);
  double* bxd              = (double*)alloc((size_t)N_ * 1024 * 4 * 8);
  double* scd              = (double*)alloc((size_t)N_ * 1024 * 8);
  int* lab                 = (int*)alloc((size_t)N_ * 1024 * 4);
  int* vld                 = (int*)alloc((size_t)N_ * 1024 * 4);
  int* rg                  = (int*)alloc((size_t)N_ * 1024 * 8 * 4);
  unsigned* keepg          = (unsigned*)alloc((size_t)N_ * 1024 * 4);
  float* msig              = (float*)alloc((size_t)N_ * HW_ * M2_ * 4);
  float* wr                = (float*)alloc((size_t)(IMH + 1) * H_ * 4);
  float* wc                = (float*)alloc((size_t)(IMW + 1) * W_ * 4);

  k_pre<<<N_ * KB + 140 + 1, 1024, 0, stream>>>(box_cls, cent, box_mask, keys, ghist, msig, wr, wc);
  k_compact<<<N_ * KB, 1024, 0, stream>>>(keys, ghist, bufK, bufI, cntG);
  k_sortdec<<<N_, 1024, 0, stream>>>(bufK, bufI, cntG, locations, box_reg, bxd, scd, lab, vld, rg, keepg);
  k_nms<<<dim3(C_, N_), 64, 0, stream>>>(bxd, lab, vld, keepg);
  k_finish<<<dim3(100, N_), 256, 0, stream>>>(keepg, bxd, scd, lab, rg, msig, wr, wc, out);
}

// Round 5
// 91.034 us; speedup vs baseline: 2.0440x; 1.2464x over previous
//
#include <hip/hip_runtime.h>

#define DEVI __device__ __forceinline__

constexpr int N_ = 2, C_ = 80, H_ = 32, W_ = 40, HW_ = H_ * W_, HWC_ = HW_ * C_;
constexpr int KTOP = 1000, M2_ = 196;
constexpr int IMH = 256, IMW = 320;
constexpr int BUFCAP = 4096;
constexpr int NB = 2048;      // float-derived bins
constexpr int KB = 16;        // hist slices per image
constexpr int SLICE = HWC_ / KB; // 6400 = 5*HW_

// output layout (floats): bx[2][100][4] | sc[2][100] | lb[2][100] | prob[2][100][196] | vf[2][100]
constexpr int O_SC = 800, O_LB = 1000, O_PB = 1200, O_VF = 40400;

DEVI unsigned long long mapd(double v) {
  unsigned long long u = (unsigned long long)__double_as_longlong(v);
  return (u & 0x8000000000000000ull) ? ~u : (u | 0x8000000000000000ull);
}
DEVI double unmapd(unsigned long long k) {
  unsigned long long u = (k & 0x8000000000000000ull) ? (k ^ 0x8000000000000000ull) : ~k;
  return __longlong_as_double((long long)u);
}
DEVI int binof(unsigned long long k) {
  double v = unmapd(k);
  unsigned b = __float_as_uint((float)v);
  int bin = (int)(b >> 16) - 0x3800;
  return bin < 0 ? 0 : (bin > NB - 1 ? NB - 1 : bin);
}
// exact first contributing mask-row/col for image coordinate x (matches k_tab arithmetic:
// scale 1/8 is exact in f32, so floor/clamp agree bitwise with the table construction)
DEVI int i0of(int x, int cap) {
  float src = ((float)x + 0.5f) * 0.125f - 0.5f;
  src = fminf(fmaxf(src, 0.f), (float)cap);
  return (int)floorf(src);
}

// ---- K1: keys + per-slice LDS hist + mask transpose/sigmoid + weight tables (proven r3) ----
__global__ __launch_bounds__(1024) void k_pre(const float* cls, const float* cent, const float* bm,
                                              unsigned long long* keys, unsigned* ghist,
                                              float* msig, float* wr, float* wc) {
  int b = blockIdx.x, tid = threadIdx.x;
  if (b < N_ * KB) {
    __shared__ unsigned hist[NB];
    __shared__ double ce[HW_];
    int n = b / KB, sb = b % KB;
    size_t base = (size_t)n * HWC_ + (size_t)sb * SLICE;
    for (int j = tid; j < NB; j += 1024) hist[j] = 0;
    for (int j = tid; j < HW_; j += 1024) ce[j] = 1.0 / (1.0 + exp(-(double)cent[n * HW_ + j]));
    __syncthreads();
    #pragma unroll
    for (int it = 0; it < 7; ++it) {
      int j = it * 1024 + tid;
      if (j < SLICE) {
        size_t t = base + j;
        int hw = j % HW_;                       // base is a multiple of HW_
        double a = (double)cls[t];
        double s = 1.0 / (1.0 + exp(-a));
        double v = (s > 0.05) ? s * ce[hw] : -1e9;
        unsigned long long k = mapd(v);
        keys[t] = k;
        if (k >> 63) atomicAdd(&hist[binof(k)], 1u);
      }
    }
    __syncthreads();
    unsigned* gh = ghist + ((size_t)n * KB + sb) * NB;
    for (int j = tid; j < NB; j += 1024) gh[j] = hist[j];
  } else if (b < N_ * KB + 140) {
    __shared__ float tile[4][32][33];
    int g = tid >> 8, sub = tid & 255;
    int tt = (b - N_ * KB) * 4 + g;             // 0..559
    int n = tt / 280, r = tt % 280, rqt = r / 7, ct = r % 7;
    int tx = sub & 31, ty = sub >> 5;           // 32x8
    int rq0 = rqt * 32, c0 = ct * 32;
    for (int i = 0; i < 4; ++i) {
      int cc = c0 + ty + i * 8, rq = rq0 + tx;
      if (cc < M2_) {
        float v = bm[((size_t)n * M2_ + cc) * HW_ + rq];
        tile[g][ty + i * 8][tx] = 1.f / (1.f + expf(-v));
      }
    }
    __syncthreads();
    for (int i = 0; i < 4; ++i) {
      int rq = rq0 + ty + i * 8, cc = c0 + tx;
      if (cc < M2_) msig[((size_t)n * HW_ + rq) * M2_ + cc] = tile[g][tx][ty + i * 8];
    }
  } else {
    int t = tid;
    if (t < H_) {
      int r = t; float acc = 0.f; wr[0 * H_ + r] = 0.f;
      for (int x = 0; x < IMH; ++x) {
        float src = ((float)x + 0.5f) * ((float)H_ / (float)IMH) - 0.5f;
        src = fminf(fmaxf(src, 0.f), (float)(H_ - 1));
        int i0 = (int)floorf(src); int i1 = min(i0 + 1, H_ - 1);
        float lam = src - (float)i0;
        float w = ((r == i0) ? (1.f - lam) : 0.f) + ((r == i1) ? lam : 0.f);
        acc += w; wr[(x + 1) * H_ + r] = acc;
      }
    } else if (t < H_ + W_) {
      int q = t - H_; float acc = 0.f; wc[0 * W_ + q] = 0.f;
      for (int y = 0; y < IMW; ++y) {
        float src = ((float)y + 0.5f) * ((float)W_ / (float)IMW) - 0.5f;
        src = fminf(fmaxf(src, 0.f), (float)(W_ - 1));
        int i0 = (int)floorf(src); int i1 = min(i0 + 1, W_ - 1);
        float lam = src - (float)i0;
        float w = ((q == i0) ? (1.f - lam) : 0.f) + ((q == i1) ? lam : 0.f);
        acc += w; wc[(y + 1) * W_ + q] = acc;
      }
    }
  }
}

// ---- K2: parallel compact — 32 blocks; each computes D redundantly, owns one slice ----
__global__ __launch_bounds__(1024) void k_compact(const unsigned long long* keys, const unsigned* ghist,
                                                  unsigned long long* bufK, unsigned* bufI, unsigned* cntG) {
  __shared__ unsigned wtot[16], wabove[16], sliceCnt[16], sliceOff[17];
  __shared__ unsigned sD, lcnt;
  int b = blockIdx.x, n = b >> 4, sb = b & 15;
  int tid = threadIdx.x, lane = tid & 63, wid = tid >> 6;
  const unsigned* gh = ghist + (size_t)n * KB * NB;
  unsigned a = 0, bv = 0;
  #pragma unroll
  for (int q = 0; q < KB; ++q) { a += gh[q * NB + 2 * tid]; bv += gh[q * NB + 2 * tid + 1]; }
  if (tid == 0) { sD = 0; lcnt = 0; }
  unsigned s = a + bv, suf = s;
  for (int off = 1; off < 64; off <<= 1) {
    unsigned v = __shfl_down(suf, off);
    if (lane + off < 64) suf += v;
  }
  if (lane == 0) wtot[wid] = suf;
  __syncthreads();
  if (tid == 0) { unsigned acc = 0; for (int w = 15; w >= 0; --w) { wabove[w] = acc; acc += wtot[w]; } }
  __syncthreads();
  unsigned above = (suf - s) + wabove[wid];
  if (above < 1000u && above + bv >= 1000u) sD = (unsigned)(2 * tid + 1);
  if (above + bv < 1000u && above + bv + a >= 1000u) sD = (unsigned)(2 * tid);
  __syncthreads();
  unsigned D = sD;

  // per-slice counts of bin >= D: wave w handles slice w
  {
    unsigned acc = 0;
    for (int bin = (int)D + lane; bin < NB; bin += 64) acc += gh[wid * NB + bin];
    for (int off = 32; off; off >>= 1) acc += __shfl_down(acc, off);
    if (lane == 0) sliceCnt[wid] = acc;
  }
  __syncthreads();
  if (tid == 0) {
    unsigned acc = 0;
    for (int q = 0; q < KB; ++q) { sliceOff[q] = acc; acc += sliceCnt[q]; }
    sliceOff[KB] = acc;
    if (sb == 0) cntG[n] = acc;
  }
  __syncthreads();
  unsigned myStart = sliceOff[sb];

  const unsigned long long* kb = keys + (size_t)n * HWC_ + (size_t)sb * SLICE;
  for (int it = 0; it < 7; ++it) {
    int j = it * 1024 + tid;
    bool win = false; unsigned long long k = 0;
    if (j < SLICE) { k = kb[j]; win = (k >> 63) && (unsigned)binof(k) >= D; }
    unsigned long long mb = __ballot(win);
    if (mb) {
      int lead = __builtin_ctzll(mb);
      unsigned offw = 0;
      if (lane == lead) offw = atomicAdd(&lcnt, (unsigned)__popcll(mb));
      offw = (unsigned)__shfl((int)offw, lead);
      if (win) {
        unsigned pos = myStart + offw + (unsigned)__popcll(mb & ((1ull << lane) - 1ull));
        if (pos < BUFCAP) {
          int hw = j % HW_, c = sb * 5 + j / HW_;        // SLICE = 5*HW_
          bufK[(size_t)n * BUFCAP + pos] = k;
          bufI[(size_t)n * BUFCAP + pos] = (unsigned)(hw * C_ + c); // logical [HW,C] index
        }
      }
    }
  }
}

// ---- K3: serial core — sort (shfl-accelerated bitonic) + f64 decode ----
struct SortSh { unsigned long long K[BUFCAP]; unsigned I[BUFCAP]; };

__global__ __launch_bounds__(1024) void k_sortdec(const unsigned long long* bufK, const unsigned* bufI,
                                                  const unsigned* cntG, const float* loc, const float* breg,
                                                  double* bxd, double* scd, int* lab, int* vld, int* rg,
                                                  unsigned* keepg) {
  __shared__ SortSh sh;
  int n = blockIdx.x, tid = threadIdx.x;
  keepg[n * 1024 + tid] = 0;
  unsigned cnt = cntG[n]; if (cnt > BUFCAP) cnt = BUFCAP;
  int P = 1024; while (P < (int)cnt) P <<= 1;
  for (int j = tid; j < P; j += 1024) {
    if (j < (int)cnt) { sh.K[j] = bufK[(size_t)n * BUFCAP + j]; sh.I[j] = bufI[(size_t)n * BUFCAP + j]; }
    else { sh.K[j] = 0ull; sh.I[j] = 0xFFFFFFFFu; }
  }
  __syncthreads();
  int E = P >> 10; // elements per thread: 1,2,4
  for (int sz = 2; sz <= P; sz <<= 1) {
    // LDS rounds for strides >= 64
    for (int st = sz >> 1; st >= 64; st >>= 1) {
      for (int p = tid; p < (P >> 1); p += 1024) {
        int i = ((p & ~(st - 1)) << 1) | (p & (st - 1));
        int j = i | st;
        bool up = ((i & sz) == 0);
        unsigned long long k1 = sh.K[i], k2 = sh.K[j];
        unsigned i1 = sh.I[i], i2 = sh.I[j];
        bool bef = (k1 > k2) || (k1 == k2 && i1 < i2);
        if (bef != up) { sh.K[i] = k2; sh.K[j] = k1; sh.I[i] = i2; sh.I[j] = i1; }
      }
      __syncthreads();
    }
    // in-wave shfl rounds for strides <= 32 (partner lane = lane^st, same wave)
    {
      int st0 = ((sz >> 1) < 32) ? (sz >> 1) : 32;
      for (int e = 0; e < E; ++e) {
        int elem = tid + (e << 10);
        unsigned long long k = sh.K[elem];
        unsigned ii = sh.I[elem];
        bool dir = ((elem & sz) == 0);
        for (int st = st0; st >= 1; st >>= 1) {
          unsigned long long ko = __shfl_xor(k, st);
          unsigned io = __shfl_xor(ii, st);
          bool low = ((elem & st) == 0);
          bool first = (k > ko) || (k == ko && ii < io);
          bool take_mine = first ^ (!low) ^ (!dir);
          if (!take_mine) { k = ko; ii = io; }
        }
        sh.K[elem] = k; sh.I[elem] = ii;
      }
      __syncthreads();
    }
  }

  // decode top-1000 (f64, exact vs np ref) -> per-candidate globals
  if (tid < KTOP) {
    unsigned long long key = sh.K[tid];
    unsigned idx = sh.I[tid];
    double v = unmapd(key);
    int valid = (v > -5e8) && (idx < (unsigned)HWC_);
    if (idx >= (unsigned)HWC_) idx = 0;
    int hw = (int)(idx / C_), c = (int)(idx % C_);
    double lx = (double)loc[hw * 2 + 0], ly = (double)loc[hw * 2 + 1];
    const float* rg4 = breg + (size_t)n * 4 * HW_;
    double r0 = (double)rg4[0 * HW_ + hw], r1 = (double)rg4[1 * HW_ + hw];
    double r2 = (double)rg4[2 * HW_ + hw], r3 = (double)rg4[3 * HW_ + hw];
    double b0 = lx - r0, b1 = ly - r1, b2 = lx + r2, b3 = ly + r3;
    double sc = valid ? sqrt(v) : 0.0;
    int bi0 = (int)b0, bi1 = (int)b1, bi2 = (int)b2, bi3 = (int)b3;
    int x1 = max(bi0, 0), x2 = min(bi2, IMH - 1), y1 = max(bi1, 0), y2 = min(bi3, IMW - 1);
    int rok = (x1 < x2) && (y1 < x2) && (y1 < y2);   // ref bug replicated
    int x1c = min(max(x1, 0), IMH), x2c = min(max(x2, 0), IMH);
    int y1c = min(max(y1, 0), IMW), y2c = min(max(y2, 0), IMW);
    int area = max((x2c - x1c) * (y2c - y1c), 1);
    double c0 = fmin(fmax(b0, 0.0), (double)(IMW - 1));
    double c1 = fmin(fmax(b1, 0.0), (double)(IMH - 1));
    double c2 = fmin(fmax(b2, 0.0), (double)(IMW - 1));
    double c3 = fmin(fmax(b3, 0.0), (double)(IMH - 1));
    size_t base = (size_t)n * 1024 + tid;
    bxd[base * 4 + 0] = c0; bxd[base * 4 + 1] = c1; bxd[base * 4 + 2] = c2; bxd[base * 4 + 3] = c3;
    scd[base] = sc; lab[base] = c + 1; vld[base] = valid;
    int* r8 = rg + base * 8;
    r8[0] = x1c; r8[1] = x2c; r8[2] = y1c; r8[3] = y2c; r8[4] = area; r8[5] = rok;
  }
}

// ---- K4: per-(image,class) greedy NMS (proven r2; 160 parallel blocks) ----
__global__ void k_nms(const double* bxd, const int* lab, const int* vld, unsigned* keepg) {
  int cls = blockIdx.x + 1, n = blockIdx.y, tid = threadIdx.x; // 64 threads = 1 wave
  __shared__ int mk[KTOP];
  __shared__ double mb0[KTOP], mb1[KTOP], mb2[KTOP], mb3[KTOP], ma[KTOP];
  __shared__ unsigned char kept[KTOP];
  int m = 0;
  for (int base = 0; base < KTOP; base += 64) {
    int t = base + tid;
    bool pred = (t < KTOP) && (lab[n * 1024 + t] == cls) && (vld[n * 1024 + t] != 0);
    unsigned long long bb = __ballot(pred);
    if (pred) {
      int pos = m + (int)__popcll(bb & ((1ull << tid) - 1ull));
      mk[pos] = t;
      const double* p = bxd + ((size_t)n * 1024 + t) * 4;
      double b0 = p[0], b1 = p[1], b2 = p[2], b3 = p[3];
      mb0[pos] = b0; mb1[pos] = b1; mb2[pos] = b2; mb3[pos] = b3;
      ma[pos] = (b2 - b0 + 1.0) * (b3 - b1 + 1.0);
      kept[pos] = 1;
    }
    m += (int)__popcll(bb);
  }
  __syncthreads();
  for (int i = 0; i < m; ++i) {
    if (kept[i]) {
      double x1 = mb0[i], y1 = mb1[i], x2 = mb2[i], y2 = mb3[i], ai = ma[i];
      for (int j = i + 1 + tid; j < m; j += 64) {
        double ltx = fmax(x1, mb0[j]), lty = fmax(y1, mb1[j]);
        double rbx = fmin(x2, mb2[j]), rby = fmin(y2, mb3[j]);
        double iw = fmax(rbx - ltx + 1.0, 0.0), ih = fmax(rby - lty + 1.0, 0.0);
        double inter = iw * ih;
        double uni = ai + ma[j] - inter;
        if (inter / fmax(uni, 1e-6) > 0.6) kept[j] = 0;
      }
    }
    __syncthreads();
  }
  for (int i = tid; i < m; i += 64) keepg[n * 1024 + mk[i]] = (unsigned)kept[i];
}

// ---- K5: fused stable partition + outputs + mask prob (tight bilinear-footprint loops) ----
__global__ __launch_bounds__(256) void k_finish(const unsigned* keepg, const double* bxd,
                                                const double* scd, const int* lab, const int* rg,
                                                const float* msig, const float* wr, const float* wc,
                                                float* out) {
  int t = blockIdx.x, n = blockIdx.y, tid = threadIdx.x, lane = tid & 63, wid = tid >> 6;
  __shared__ int lsel[100], lvf[100];
  __shared__ unsigned woff[4]; __shared__ unsigned sS;
  __shared__ float A[H_], B[W_];

  int i0 = tid * 4;
  unsigned ff[4]; int lc = 0;
  for (int j = 0; j < 4; ++j) {
    int i = i0 + j;
    ff[j] = (i < KTOP) ? keepg[n * 1024 + i] : 0u;
    lc += (int)ff[j];
  }
  unsigned pre = (unsigned)lc;
  for (int off = 1; off < 64; off <<= 1) {
    unsigned v = __shfl_up(pre, off);
    if (lane >= off) pre += v;
  }
  if (lane == 63) woff[wid] = pre;
  __syncthreads();
  if (tid == 0) { unsigned acc = 0; for (int w = 0; w < 4; ++w) { unsigned tmp = woff[w]; woff[w] = acc; acc += tmp; } sS = acc; }
  __syncthreads();
  int kpre = (int)(woff[wid] + pre - (unsigned)lc);
  int S = (int)sS;
  for (int j = 0; j < 4; ++j) {
    int i = i0 + j;
    if (i < KTOP) {
      if (ff[j]) { if (kpre < 100) { lsel[kpre] = i; lvf[kpre] = 1; } kpre++; }
      else { int slot = S + (i - kpre); if (slot < 100) { lsel[slot] = i; lvf[slot] = 0; } }
    }
  }
  __syncthreads();

  int k = lsel[t], vf = lvf[t];
  if (tid == 0) {
    const double* bb = bxd + ((size_t)n * 1024 + k) * 4;
    out[(n * 100 + t) * 4 + 0] = (float)bb[0];
    out[(n * 100 + t) * 4 + 1] = (float)bb[1];
    out[(n * 100 + t) * 4 + 2] = (float)bb[2];
    out[(n * 100 + t) * 4 + 3] = (float)bb[3];
    out[O_SC + n * 100 + t] = vf ? (float)scd[n * 1024 + k] : 0.f;
    out[O_LB + n * 100 + t] = (float)lab[n * 1024 + k];
    out[O_VF + n * 100 + t] = (float)vf;
  }
  const int* r8 = rg + ((size_t)n * 1024 + k) * 8;
  int x1c = r8[0], x2c = r8[1], y1c = r8[2], y2c = r8[3], area = r8[4], rok = r8[5];
  if (tid < H_) A[tid] = wr[x2c * H_ + tid] - wr[x1c * H_ + tid];
  else if (tid < H_ + W_) { int q = tid - H_; B[q] = wc[y2c * W_ + q] - wc[y1c * W_ + q]; }
  __syncthreads();
  if (tid < M2_) {
    float acc = 0.f;
    if (rok && vf) {
      // tight bilinear footprint: A[r]==0 outside [rlo,rhi], B[q]==0 outside [qlo,qhi];
      // edge terms inside the range can be 0-weight -> adding 0.0f is exact, sum order of
      // nonzero terms unchanged vs full guarded sweep.
      int rlo = i0of(x1c, H_ - 1);
      int rhi = min(i0of(x2c - 1, H_ - 1) + 1, H_ - 1);
      int qlo = i0of(y1c, W_ - 1);
      int qhi = min(i0of(y2c - 1, W_ - 1) + 1, W_ - 1);
      for (int r = rlo; r <= rhi; ++r) {
        float ar = A[r];
        const float* mrow = msig + ((size_t)((n * H_ + r) * W_ + qlo)) * M2_ + tid;
        float rs = 0.f;
        #pragma unroll 4
        for (int q = qlo; q <= qhi; ++q) { rs += B[q] * mrow[0]; mrow += M2_; }
        acc += ar * rs;
      }
      acc /= (float)area;
    }
    out[O_PB + (size_t)(n * 100 + t) * M2_ + tid] = acc;
  }
}

extern "C" void kernel_launch(void* const* d_in, const int* in_sizes, int n_in,
                              void* d_out, int out_size, void* d_ws, size_t ws_size,
                              hipStream_t stream) {
  (void)in_sizes; (void)n_in; (void)out_size; (void)ws_size;
  const float* locations = (const float*)d_in[0];
  const float* box_cls   = (const float*)d_in[1];
  const float* box_reg   = (const float*)d_in[2];
  const float* cent      = (const float*)d_in[3];
  const float* box_mask  = (const float*)d_in[4];
  float* out = (float*)d_out;

  char* ws = (char*)d_ws;
  size_t off = 0;
  auto alloc = [&](size_t bytes) -> void* {
    void* p = ws + off;
    off = (off + bytes + 255) & ~(size_t)255;
    return p;
  };
  unsigned long long* keys = (unsigned long long*)alloc((size_t)N_ * HWC_ * 8);
  unsigned* ghist          = (unsigned*)alloc((size_t)N_ * KB * NB * 4);
  unsigned long long* bufK = (unsigned long long*)alloc((size_t)N_ * BUFCAP * 8);
  unsigned* bufI           = (unsigned*)alloc((size_t)N_ * BUFCAP * 4);
  unsigned* cntG           = (unsigned*)alloc(16 * 4);
  double* bxd              = (double*)alloc((size_t)N_ * 1024 * 4 * 8);
  double* scd              = (double*)alloc((size_t)N_ * 1024 * 8);
  int* lab                 = (int*)alloc((size_t)N_ * 1024 * 4);
  int* vld                 = (int*)alloc((size_t)N_ * 1024 * 4);
  int* rg                  = (int*)alloc((size_t)N_ * 1024 * 8 * 4);
  unsigned* keepg          = (unsigned*)alloc((size_t)N_ * 1024 * 4);
  float* msig              = (float*)alloc((size_t)N_ * HW_ * M2_ * 4);
  float* wr                = (float*)alloc((size_t)(IMH + 1) * H_ * 4);
  float* wc                = (float*)alloc((size_t)(IMW + 1) * W_ * 4);

  k_pre<<<N_ * KB + 140 + 1, 1024, 0, stream>>>(box_cls, cent, box_mask, keys, ghist, msig, wr, wc);
  k_compact<<<N_ * KB, 1024, 0, stream>>>(keys, ghist, bufK, bufI, cntG);
  k_sortdec<<<N_, 1024, 0, stream>>>(bufK, bufI, cntG, locations, box_reg, bxd, scd, lab, vld, rg, keepg);
  k_nms<<<dim3(C_, N_), 64, 0, stream>>>(bxd, lab, vld, keepg);
  k_finish<<<dim3(100, N_), 256, 0, stream>>>(keepg, bxd, scd, lab, rg, msig, wr, wc, out);
}